// Round 5
// baseline (533.897 us; speedup 1.0000x reference)
//
#include <hip/hip_runtime.h>

#define NEG_SLOPE 0.2f

typedef __bf16 bf16x8 __attribute__((ext_vector_type(8)));
typedef float floatx4 __attribute__((ext_vector_type(4)));
typedef unsigned short ushortx4 __attribute__((ext_vector_type(4)));

__device__ __forceinline__ float eluf(float x) { return x > 0.f ? x : __expf(x) - 1.f; }
__device__ __forceinline__ float lrelu(float x) { return x > 0.f ? x : NEG_SLOPE * x; }

__device__ __forceinline__ unsigned short f2bf(float f) {
    unsigned u = __float_as_uint(f);
    u += 0x7FFFu + ((u >> 16) & 1u);           // round-to-nearest-even
    return (unsigned short)(u >> 16);
}
__device__ __forceinline__ float bf2f(unsigned short h) {
    return __uint_as_float(((unsigned)h) << 16);
}

// ---------------- CSR build (dst-sorted adjacency, self-loops appended) ----------------
__global__ void count_kernel(const int* __restrict__ ei, int E, int N, int* __restrict__ counts) {
    int i = blockIdx.x * blockDim.x + threadIdx.x;
    int Et = E + N;
    if (i >= Et) return;
    int d = (i < E) ? ei[E + i] : (i - E);
    atomicAdd(&counts[d], 1);
}

// single 1024-thread block; wave-shuffle scan
__global__ void scan_kernel(int* __restrict__ counts_cursor, int* __restrict__ row_ptr, int N) {
    __shared__ int s_wsum[16];
    __shared__ int s_carry;
    int t = threadIdx.x;
    int lane = t & 63, wid = t >> 6;
    if (t == 0) { s_carry = 0; row_ptr[0] = 0; }
    __syncthreads();
    for (int start = 0; start < N; start += 1024) {
        int i = start + t;
        int v = (i < N) ? counts_cursor[i] : 0;
        int s = v;
        #pragma unroll
        for (int d = 1; d < 64; d <<= 1) {
            int u = __shfl_up(s, d);
            if (lane >= d) s += u;
        }
        if (lane == 63) s_wsum[wid] = s;
        __syncthreads();
        if (wid == 0) {
            int w = (lane < 16) ? s_wsum[lane] : 0;
            #pragma unroll
            for (int d = 1; d < 16; d <<= 1) {
                int u = __shfl_up(w, d);
                if (lane >= d) w += u;
            }
            if (lane < 16) s_wsum[lane] = w;
        }
        __syncthreads();
        int incl = s + (wid ? s_wsum[wid - 1] : 0) + s_carry;
        if (i < N) { row_ptr[i + 1] = incl; counts_cursor[i] = incl - v; }
        __syncthreads();
        if (t == 0) s_carry += s_wsum[15];
        __syncthreads();
    }
}

__global__ void fill_kernel(const int* __restrict__ ei, int E, int N,
                            int* __restrict__ cursor, int* __restrict__ col) {
    int i = blockIdx.x * blockDim.x + threadIdx.x;
    int Et = E + N;
    if (i >= Et) return;
    int s, d;
    if (i < E) { s = ei[i]; d = ei[E + i]; } else { s = d = i - E; }
    int pos = atomicAdd(&cursor[d], 1);
    col[pos] = s;
}

// ---------------- fp32 -> bf16 convert (x, done once so GEMM1 A-reads are 2B/elem) ----------------
__global__ void convert_bf16(const float* __restrict__ in, unsigned short* __restrict__ outb, int len4) {
    int i = blockIdx.x * blockDim.x + threadIdx.x;
    if (i >= len4) return;
    float4 v = ((const float4*)in)[i];
    ushortx4 o;
    o[0] = f2bf(v.x); o[1] = f2bf(v.y); o[2] = f2bf(v.z); o[3] = f2bf(v.w);
    *(ushortx4*)(outb + (size_t)i * 4) = o;
}

// ---------------- transpose + split: B[K][N] fp32 -> T[N][K] bf16 hi/lo ----------------
__global__ __launch_bounds__(256) void transpose_split(const float* __restrict__ B,
        unsigned short* __restrict__ Th, unsigned short* __restrict__ Tl, int K, int N) {
    __shared__ float tile[32][33];
    int n0 = blockIdx.x * 32, k0 = blockIdx.y * 32;
    int tx = threadIdx.x, ty = threadIdx.y;  // block (32, 8)
    #pragma unroll
    for (int i = 0; i < 32; i += 8)
        tile[ty + i][tx] = B[(size_t)(k0 + ty + i) * N + n0 + tx];
    __syncthreads();
    #pragma unroll
    for (int i = 0; i < 32; i += 8) {
        float v = tile[tx][ty + i];
        unsigned short h = f2bf(v);
        unsigned short l = f2bf(v - bf2f(h));
        size_t idx = (size_t)(n0 + ty + i) * K + k0 + tx;
        Th[idx] = h; Tl[idx] = l;
    }
}

// ---------------- 2-term split-bf16 MFMA GEMM: C = A @ (Bh+Bl)^T ----------------
// A: bf16 bits [M][K]. B arrays: [N][K] (B^T) hi/lo. 128xTN tile, BK=32, 4 waves.
#define LDK 40  // 32 + 8 pad (shorts) -> 80 B row stride, 2-way (free) frag-read conflicts
template <bool OUT_BF16, int TN>
__global__ __launch_bounds__(256) void gemm_2t(const unsigned short* __restrict__ A,
        const unsigned short* __restrict__ Bh, const unsigned short* __restrict__ Bl,
        void* __restrict__ Cout, int M, int N, int K) {
    constexpr int JN = TN / 32;                  // B frags per wave (TN=128 -> 4, TN=64 -> 2)
    __shared__ unsigned short As[128 * LDK];
    __shared__ unsigned short Bs[2][TN * LDK];
    int t = threadIdx.x;
    int lane = t & 63, wave = t >> 6;
    int wm = (wave >> 1) * 64, wn = (wave & 1) * (TN / 2);
    int q = lane >> 4, l16 = lane & 15;
    int row0 = blockIdx.y * 128, col0 = blockIdx.x * TN;

    floatx4 acc[4][JN] = {};

    int sg = (t & 7) * 4;   // k-offset (4-elem granule)
    int sr = t >> 3;        // row 0..31 per pass

    for (int kt = 0; kt < K; kt += 32) {
        #pragma unroll
        for (int p = 0; p < 4; p++) {
            int r = sr + p * 32;
            int ga = min(row0 + r, M - 1);        // clamp ragged M (stores are guarded)
            *(ushortx4*)&As[r * LDK + sg] = *(const ushortx4*)(A + (size_t)ga * K + kt + sg);
        }
        #pragma unroll
        for (int p = 0; p < TN / 32; p++) {
            int r = sr + p * 32;
            size_t gob = (size_t)(col0 + r) * K + kt + sg;  // N multiple of TN
            *(ushortx4*)&Bs[0][r * LDK + sg] = *(const ushortx4*)(Bh + gob);
            *(ushortx4*)&Bs[1][r * LDK + sg] = *(const ushortx4*)(Bl + gob);
        }
        __syncthreads();
        bf16x8 af[4], bfr[JN][2];
        #pragma unroll
        for (int i = 0; i < 4; i++)
            af[i] = *(const bf16x8*)&As[(wm + i * 16 + l16) * LDK + q * 8];
        #pragma unroll
        for (int j = 0; j < JN; j++) {
            bfr[j][0] = *(const bf16x8*)&Bs[0][(wn + j * 16 + l16) * LDK + q * 8];
            bfr[j][1] = *(const bf16x8*)&Bs[1][(wn + j * 16 + l16) * LDK + q * 8];
        }
        #pragma unroll
        for (int i = 0; i < 4; i++)
            #pragma unroll
            for (int j = 0; j < JN; j++) {
                acc[i][j] = __builtin_amdgcn_mfma_f32_16x16x32_bf16(af[i], bfr[j][0], acc[i][j], 0, 0, 0);
                acc[i][j] = __builtin_amdgcn_mfma_f32_16x16x32_bf16(af[i], bfr[j][1], acc[i][j], 0, 0, 0);
            }
        __syncthreads();
    }
    #pragma unroll
    for (int i = 0; i < 4; i++) {
        #pragma unroll
        for (int r = 0; r < 4; r++) {
            int grow = row0 + wm + i * 16 + q * 4 + r;
            if (grow < M) {
                if constexpr (OUT_BF16) {
                    unsigned short* cp = (unsigned short*)Cout + (size_t)grow * N + col0 + wn + l16;
                    #pragma unroll
                    for (int j = 0; j < JN; j++) cp[j * 16] = f2bf(acc[i][j][r]);
                } else {
                    float* cp = (float*)Cout + (size_t)grow * N + col0 + wn + l16;
                    #pragma unroll
                    for (int j = 0; j < JN; j++) cp[j * 16] = acc[i][j][r];
                }
            }
        }
    }
}

// ---------------- per-node attention logits, layer 1 (H=4, C=256), bf16 h1 ----------------
__global__ void s1_kernel(const unsigned short* __restrict__ h1b, const float* __restrict__ a_src,
                          const float* __restrict__ a_dst, float* __restrict__ ssrc,
                          float* __restrict__ sdst, int N) {
    int wid = (blockIdx.x * blockDim.x + threadIdx.x) >> 6;
    int lane = threadIdx.x & 63;
    if (wid >= N) return;
    const unsigned short* row = h1b + (size_t)wid * 1024;
    #pragma unroll
    for (int h = 0; h < 4; h++) {
        ushortx4 v = *(const ushortx4*)(row + h * 256 + lane * 4);
        float4 a = ((const float4*)a_src)[h * 64 + lane];
        float4 d = ((const float4*)a_dst)[h * 64 + lane];
        float v0 = bf2f(v[0]), v1 = bf2f(v[1]), v2 = bf2f(v[2]), v3 = bf2f(v[3]);
        float s = v0 * a.x + v1 * a.y + v2 * a.z + v3 * a.w;
        float t = v0 * d.x + v1 * d.y + v2 * d.z + v3 * d.w;
        for (int off = 32; off; off >>= 1) { s += __shfl_xor(s, off); t += __shfl_xor(t, off); }
        if (lane == 0) { ssrc[wid * 4 + h] = s; sdst[wid * 4 + h] = t; }
    }
}

// ---------------- per-node attention logits, layer 2 (H=1, C=256), bf16 h2 ----------------
__global__ void s2_kernel(const unsigned short* __restrict__ h2b, const float* __restrict__ a_src,
                          const float* __restrict__ a_dst, float* __restrict__ ssrc,
                          float* __restrict__ sdst, int N) {
    int wid = (blockIdx.x * blockDim.x + threadIdx.x) >> 6;
    int lane = threadIdx.x & 63;
    if (wid >= N) return;
    ushortx4 v = *(const ushortx4*)(h2b + (size_t)wid * 256 + lane * 4);
    float4 a = ((const float4*)a_src)[lane];
    float4 d = ((const float4*)a_dst)[lane];
    float v0 = bf2f(v[0]), v1 = bf2f(v[1]), v2 = bf2f(v[2]), v3 = bf2f(v[3]);
    float s = v0 * a.x + v1 * a.y + v2 * a.z + v3 * a.w;
    float t = v0 * d.x + v1 * d.y + v2 * d.z + v3 * d.w;
    for (int off = 32; off; off >>= 1) { s += __shfl_xor(s, off); t += __shfl_xor(t, off); }
    if (lane == 0) { ssrc[wid] = s; sdst[wid] = t; }
}

// ---------------- per-edge softmax weights, layer 1 (H=4): wx[e][h]=exp(e-m), den[dst][h] ----------------
__global__ __launch_bounds__(256) void alpha1_kernel(const float* __restrict__ ssrc,
        const float* __restrict__ sdst, const int* __restrict__ row_ptr,
        const int* __restrict__ col, float* __restrict__ wx, float* __restrict__ den, int N) {
    int wid = (blockIdx.x * blockDim.x + threadIdx.x) >> 6;
    int lane = threadIdx.x & 63;
    if (wid >= N) return;
    int base = row_ptr[wid];
    int deg = row_ptr[wid + 1] - base;
    float sd0 = sdst[wid * 4 + 0], sd1 = sdst[wid * 4 + 1];
    float sd2 = sdst[wid * 4 + 2], sd3 = sdst[wid * 4 + 3];
    float m0 = -1e30f, m1 = -1e30f, m2 = -1e30f, m3 = -1e30f;
    for (int i = lane; i < deg; i += 64) {
        int s = col[base + i];
        const float* sp = ssrc + s * 4;
        m0 = fmaxf(m0, lrelu(sp[0] + sd0));
        m1 = fmaxf(m1, lrelu(sp[1] + sd1));
        m2 = fmaxf(m2, lrelu(sp[2] + sd2));
        m3 = fmaxf(m3, lrelu(sp[3] + sd3));
    }
    #pragma unroll
    for (int off = 32; off; off >>= 1) {
        m0 = fmaxf(m0, __shfl_xor(m0, off));
        m1 = fmaxf(m1, __shfl_xor(m1, off));
        m2 = fmaxf(m2, __shfl_xor(m2, off));
        m3 = fmaxf(m3, __shfl_xor(m3, off));
    }
    float d0 = 0.f, d1 = 0.f, d2 = 0.f, d3 = 0.f;
    for (int i = lane; i < deg; i += 64) {
        int s = col[base + i];
        const float* sp = ssrc + s * 4;
        float4 w4;
        w4.x = __expf(lrelu(sp[0] + sd0) - m0); d0 += w4.x;
        w4.y = __expf(lrelu(sp[1] + sd1) - m1); d1 += w4.y;
        w4.z = __expf(lrelu(sp[2] + sd2) - m2); d2 += w4.z;
        w4.w = __expf(lrelu(sp[3] + sd3) - m3); d3 += w4.w;
        *(float4*)(wx + (size_t)(base + i) * 4) = w4;
    }
    #pragma unroll
    for (int off = 32; off; off >>= 1) {
        d0 += __shfl_xor(d0, off);
        d1 += __shfl_xor(d1, off);
        d2 += __shfl_xor(d2, off);
        d3 += __shfl_xor(d3, off);
    }
    if (lane == 0) {
        den[wid * 4 + 0] = d0; den[wid * 4 + 1] = d1;
        den[wid * 4 + 2] = d2; den[wid * 4 + 3] = d3;
    }
}

// ---------------- per-edge softmax weights, layer 2 (H=1) ----------------
__global__ __launch_bounds__(256) void alpha2_kernel(const float* __restrict__ ssrc,
        const float* __restrict__ sdst, const int* __restrict__ row_ptr,
        const int* __restrict__ col, float* __restrict__ wx, float* __restrict__ den, int N) {
    int wid = (blockIdx.x * blockDim.x + threadIdx.x) >> 6;
    int lane = threadIdx.x & 63;
    if (wid >= N) return;
    int base = row_ptr[wid];
    int deg = row_ptr[wid + 1] - base;
    float sd = sdst[wid];
    float m = -1e30f;
    for (int i = lane; i < deg; i += 64) {
        int s = col[base + i];
        m = fmaxf(m, lrelu(ssrc[s] + sd));
    }
    #pragma unroll
    for (int off = 32; off; off >>= 1) m = fmaxf(m, __shfl_xor(m, off));
    float d = 0.f;
    for (int i = lane; i < deg; i += 64) {
        int s = col[base + i];
        float x = __expf(lrelu(ssrc[s] + sd) - m);
        d += x;
        wx[base + i] = x;
    }
    #pragma unroll
    for (int off = 32; off; off >>= 1) d += __shfl_xor(d, off);
    if (lane == 0) den[wid] = d;
}

// ---------------- layer-1 aggregation: pure gather+FMA; bf16 out ----------------
__global__ __launch_bounds__(256) void agg1_kernel(const unsigned short* __restrict__ h1b,
        const float* __restrict__ wx, const float* __restrict__ den,
        const int* __restrict__ row_ptr, const int* __restrict__ col,
        const float* __restrict__ bias, unsigned short* __restrict__ outb, int N) {
    int wid = (blockIdx.x * blockDim.x + threadIdx.x) >> 6;
    int lane = threadIdx.x & 63;
    if (wid >= N) return;
    int base = row_ptr[wid];
    int deg = row_ptr[wid + 1] - base;
    float4 a0 = {0,0,0,0}, a1 = {0,0,0,0}, a2 = {0,0,0,0}, a3 = {0,0,0,0};
    int c = lane * 4;
    for (int i = 0; i < deg; i++) {
        int s = col[base + i];
        float4 xa = *(const float4*)(wx + (size_t)(base + i) * 4);  // wave-uniform broadcast
        const unsigned short* row = h1b + (size_t)s * 1024;
        ushortx4 v;
        v = *(const ushortx4*)(row + c);
        a0.x += xa.x * bf2f(v[0]); a0.y += xa.x * bf2f(v[1]); a0.z += xa.x * bf2f(v[2]); a0.w += xa.x * bf2f(v[3]);
        v = *(const ushortx4*)(row + 256 + c);
        a1.x += xa.y * bf2f(v[0]); a1.y += xa.y * bf2f(v[1]); a1.z += xa.y * bf2f(v[2]); a1.w += xa.y * bf2f(v[3]);
        v = *(const ushortx4*)(row + 512 + c);
        a2.x += xa.z * bf2f(v[0]); a2.y += xa.z * bf2f(v[1]); a2.z += xa.z * bf2f(v[2]); a2.w += xa.z * bf2f(v[3]);
        v = *(const ushortx4*)(row + 768 + c);
        a3.x += xa.w * bf2f(v[0]); a3.y += xa.w * bf2f(v[1]); a3.z += xa.w * bf2f(v[2]); a3.w += xa.w * bf2f(v[3]);
    }
    float i0 = 1.f / (den[wid * 4 + 0] + 1e-16f), i1 = 1.f / (den[wid * 4 + 1] + 1e-16f);
    float i2 = 1.f / (den[wid * 4 + 2] + 1e-16f), i3 = 1.f / (den[wid * 4 + 3] + 1e-16f);
    size_t ob = (size_t)wid * 1024;
    ushortx4 w;
    w[0] = f2bf(eluf(a0.x * i0 + bias[c + 0])); w[1] = f2bf(eluf(a0.y * i0 + bias[c + 1]));
    w[2] = f2bf(eluf(a0.z * i0 + bias[c + 2])); w[3] = f2bf(eluf(a0.w * i0 + bias[c + 3]));
    *(ushortx4*)(outb + ob + c) = w;
    w[0] = f2bf(eluf(a1.x * i1 + bias[256 + c + 0])); w[1] = f2bf(eluf(a1.y * i1 + bias[256 + c + 1]));
    w[2] = f2bf(eluf(a1.z * i1 + bias[256 + c + 2])); w[3] = f2bf(eluf(a1.w * i1 + bias[256 + c + 3]));
    *(ushortx4*)(outb + ob + 256 + c) = w;
    w[0] = f2bf(eluf(a2.x * i2 + bias[512 + c + 0])); w[1] = f2bf(eluf(a2.y * i2 + bias[512 + c + 1]));
    w[2] = f2bf(eluf(a2.z * i2 + bias[512 + c + 2])); w[3] = f2bf(eluf(a2.w * i2 + bias[512 + c + 3]));
    *(ushortx4*)(outb + ob + 512 + c) = w;
    w[0] = f2bf(eluf(a3.x * i3 + bias[768 + c + 0])); w[1] = f2bf(eluf(a3.y * i3 + bias[768 + c + 1]));
    w[2] = f2bf(eluf(a3.z * i3 + bias[768 + c + 2])); w[3] = f2bf(eluf(a3.w * i3 + bias[768 + c + 3]));
    *(ushortx4*)(outb + ob + 768 + c) = w;
}

// ---------------- layer-2 aggregation: pure gather+FMA; fp32 out ----------------
__global__ __launch_bounds__(256) void agg2_kernel(const unsigned short* __restrict__ h2b,
        const float* __restrict__ wx, const float* __restrict__ den,
        const int* __restrict__ row_ptr, const int* __restrict__ col,
        const float* __restrict__ bias, float* __restrict__ out, int N) {
    int wid = (blockIdx.x * blockDim.x + threadIdx.x) >> 6;
    int lane = threadIdx.x & 63;
    if (wid >= N) return;
    int base = row_ptr[wid];
    int deg = row_ptr[wid + 1] - base;
    float4 a = {0,0,0,0};
    int c = lane * 4;
    for (int i = 0; i < deg; i++) {
        int s = col[base + i];
        float x = wx[base + i];
        ushortx4 v = *(const ushortx4*)(h2b + (size_t)s * 256 + c);
        a.x += x * bf2f(v[0]); a.y += x * bf2f(v[1]);
        a.z += x * bf2f(v[2]); a.w += x * bf2f(v[3]);
    }
    float inv = 1.f / (den[wid] + 1e-16f);
    float4 o;
    o.x = eluf(a.x * inv + bias[c + 0]);
    o.y = eluf(a.y * inv + bias[c + 1]);
    o.z = eluf(a.z * inv + bias[c + 2]);
    o.w = eluf(a.w * inv + bias[c + 3]);
    *(float4*)(out + (size_t)wid * 256 + c) = o;
}

// ---------------- mean over nodes -> graph_features [256] ----------------
__global__ void mean_kernel(const float* __restrict__ h, float* __restrict__ gf, int N) {
    int c = threadIdx.x;
    int per = (N + gridDim.x - 1) / gridDim.x;
    int n0 = blockIdx.x * per;
    int n1 = min(N, n0 + per);
    float acc = 0.f;
    for (int n = n0; n < n1; n++) acc += h[(size_t)n * 256 + c];
    atomicAdd(&gf[c], acc * (1.0f / N));
}

// ---------------- influence head: sigmoid(relu(h@Wp1+bp1)@Wp2+bp2), 4 nodes/block ----------------
__global__ __launch_bounds__(128) void infl_kernel(const float* __restrict__ h,
        const float* __restrict__ Wp1, const float* __restrict__ bp1,
        const float* __restrict__ Wp2, const float* __restrict__ bp2,
        float* __restrict__ infl, int N) {
    __shared__ float sh[4][256];
    __shared__ float red[4][128];
    int nb = blockIdx.x * 4;
    int t = threadIdx.x;
    #pragma unroll
    for (int r = 0; r < 4; r++) {
        int n = nb + r;
        if (n < N) {
            sh[r][t] = h[(size_t)n * 256 + t];
            sh[r][t + 128] = h[(size_t)n * 256 + t + 128];
        }
    }
    __syncthreads();
    float acc0 = bp1[t], acc1 = acc0, acc2 = acc0, acc3 = acc0;
    for (int k = 0; k < 256; k++) {
        float w = Wp1[k * 128 + t];
        acc0 += sh[0][k] * w;
        acc1 += sh[1][k] * w;
        acc2 += sh[2][k] * w;
        acc3 += sh[3][k] * w;
    }
    float w2 = Wp2[t];
    red[0][t] = fmaxf(acc0, 0.f) * w2;
    red[1][t] = fmaxf(acc1, 0.f) * w2;
    red[2][t] = fmaxf(acc2, 0.f) * w2;
    red[3][t] = fmaxf(acc3, 0.f) * w2;
    __syncthreads();
    for (int s = 64; s > 0; s >>= 1) {
        if (t < s) {
            red[0][t] += red[0][t + s];
            red[1][t] += red[1][t + s];
            red[2][t] += red[2][t + s];
            red[3][t] += red[3][t + s];
        }
        __syncthreads();
    }
    if (t < 4) {
        int n = nb + t;
        if (n < N) {
            float v = red[t][0] + bp2[0];
            infl[n] = 1.f / (1.f + __expf(-v));
        }
    }
}

extern "C" void kernel_launch(void* const* d_in, const int* in_sizes, int n_in,
                              void* d_out, int out_size, void* d_ws, size_t ws_size,
                              hipStream_t stream) {
    const float* x   = (const float*)d_in[0];
    const int*   ei  = (const int*)d_in[1];
    const float* W1  = (const float*)d_in[2];
    const float* as1 = (const float*)d_in[3];
    const float* ad1 = (const float*)d_in[4];
    const float* b1  = (const float*)d_in[5];
    const float* W2  = (const float*)d_in[6];
    const float* as2 = (const float*)d_in[7];
    const float* ad2 = (const float*)d_in[8];
    const float* b2  = (const float*)d_in[9];
    const float* Wp1 = (const float*)d_in[10];
    const float* bp1 = (const float*)d_in[11];
    const float* Wp2 = (const float*)d_in[12];
    const float* bp2 = (const float*)d_in[13];

    const int N  = in_sizes[0] / 384;   // 20000
    const int E  = in_sizes[1] / 2;     // 320000
    const int Et = E + N;

    // ---- workspace layout (~120 MB) ----
    char* wsp = (char*)d_ws;
    unsigned short* h1b  = (unsigned short*)wsp; wsp += (size_t)N * 1024 * sizeof(short); // GEMM1 out, bf16
    unsigned short* h1eb = (unsigned short*)wsp; wsp += (size_t)N * 1024 * sizeof(short); // agg1 out, bf16
    unsigned short* h2b  = (unsigned short*)wsp; wsp += (size_t)N * 256  * sizeof(short); // GEMM2 out, bf16
    unsigned short* xb   = (unsigned short*)wsp; wsp += (size_t)N * 384  * sizeof(short); // x, bf16
    unsigned short* w1th = (unsigned short*)wsp; wsp += (size_t)1024 * 384 * sizeof(short);
    unsigned short* w1tl = (unsigned short*)wsp; wsp += (size_t)1024 * 384 * sizeof(short);
    unsigned short* w2th = (unsigned short*)wsp; wsp += (size_t)256 * 1024 * sizeof(short);
    unsigned short* w2tl = (unsigned short*)wsp; wsp += (size_t)256 * 1024 * sizeof(short);
    float* ss1 = (float*)wsp; wsp += (size_t)N * 4 * sizeof(float);
    float* sd1 = (float*)wsp; wsp += (size_t)N * 4 * sizeof(float);
    float* ss2 = (float*)wsp; wsp += (size_t)N * sizeof(float);
    float* sd2 = (float*)wsp; wsp += (size_t)N * sizeof(float);
    float* den1 = (float*)wsp; wsp += (size_t)N * 4 * sizeof(float);
    float* den2 = (float*)wsp; wsp += (size_t)N * sizeof(float);
    float* wx1  = (float*)wsp; wsp += (size_t)Et * 4 * sizeof(float);
    float* wx2  = (float*)wsp; wsp += (size_t)Et * sizeof(float);
    int* row_ptr = (int*)wsp; wsp += (size_t)(N + 1) * sizeof(int);
    int* cursor  = (int*)wsp; wsp += (size_t)N * sizeof(int);
    int* col     = (int*)wsp;

    float* out_h  = (float*)d_out;             // [N,256]
    float* out_gf = out_h + (size_t)N * 256;   // [256]
    float* out_if = out_gf + 256;              // [N]

    // CSR build
    hipMemsetAsync(cursor, 0, (size_t)N * sizeof(int), stream);
    count_kernel<<<(Et + 255) / 256, 256, 0, stream>>>(ei, E, N, cursor);
    scan_kernel<<<1, 1024, 0, stream>>>(cursor, row_ptr, N);
    fill_kernel<<<(Et + 255) / 256, 256, 0, stream>>>(ei, E, N, cursor, col);

    // input/weight prep
    convert_bf16<<<(N * 384 / 4 + 255) / 256, 256, 0, stream>>>(x, xb, N * 384 / 4);
    transpose_split<<<dim3(1024 / 32, 384 / 32), dim3(32, 8), 0, stream>>>(W1, w1th, w1tl, 384, 1024);
    transpose_split<<<dim3(256 / 32, 1024 / 32), dim3(32, 8), 0, stream>>>(W2, w2th, w2tl, 1024, 256);

    // layer 1
    gemm_2t<true, 128><<<dim3(1024 / 128, (N + 127) / 128), 256, 0, stream>>>(
        xb, w1th, w1tl, h1b, N, 1024, 384);
    s1_kernel<<<(N + 3) / 4, 256, 0, stream>>>(h1b, as1, ad1, ss1, sd1, N);
    alpha1_kernel<<<(N + 3) / 4, 256, 0, stream>>>(ss1, sd1, row_ptr, col, wx1, den1, N);
    agg1_kernel<<<(N + 3) / 4, 256, 0, stream>>>(h1b, wx1, den1, row_ptr, col, b1, h1eb, N);

    // layer 2
    gemm_2t<true, 64><<<dim3(256 / 64, (N + 127) / 128), 256, 0, stream>>>(
        h1eb, w2th, w2tl, h2b, N, 256, 1024);
    s2_kernel<<<(N + 3) / 4, 256, 0, stream>>>(h2b, as2, ad2, ss2, sd2, N);
    alpha2_kernel<<<(N + 3) / 4, 256, 0, stream>>>(ss2, sd2, row_ptr, col, wx2, den2, N);
    agg2_kernel<<<(N + 3) / 4, 256, 0, stream>>>(h2b, wx2, den2, row_ptr, col, b2, out_h, N);

    // outputs 2 & 3
    hipMemsetAsync(out_gf, 0, 256 * sizeof(float), stream);
    mean_kernel<<<80, 256, 0, stream>>>(out_h, out_gf, N);
    infl_kernel<<<(N + 3) / 4, 128, 0, stream>>>(out_h, Wp1, bp1, Wp2, bp2, out_if, N);
}

// Round 6
// 514.954 us; speedup vs baseline: 1.0368x; 1.0368x over previous
//
#include <hip/hip_runtime.h>

#define NEG_SLOPE 0.2f

typedef __bf16 bf16x8 __attribute__((ext_vector_type(8)));
typedef float floatx4 __attribute__((ext_vector_type(4)));
typedef unsigned short ushortx4 __attribute__((ext_vector_type(4)));
typedef unsigned short ushortx8 __attribute__((ext_vector_type(8)));

__device__ __forceinline__ float eluf(float x) { return x > 0.f ? x : __expf(x) - 1.f; }
__device__ __forceinline__ float lrelu(float x) { return x > 0.f ? x : NEG_SLOPE * x; }

__device__ __forceinline__ unsigned short f2bf(float f) {
    unsigned u = __float_as_uint(f);
    u += 0x7FFFu + ((u >> 16) & 1u);           // round-to-nearest-even
    return (unsigned short)(u >> 16);
}
__device__ __forceinline__ float bf2f(unsigned short h) {
    return __uint_as_float(((unsigned)h) << 16);
}

// ---------------- CSR build (dst-sorted adjacency, self-loops appended) ----------------
__global__ void count_kernel(const int* __restrict__ ei, int E, int N, int* __restrict__ counts) {
    int i = blockIdx.x * blockDim.x + threadIdx.x;
    int Et = E + N;
    if (i >= Et) return;
    int d = (i < E) ? ei[E + i] : (i - E);
    atomicAdd(&counts[d], 1);
}

// single 1024-thread block; wave-shuffle scan
__global__ void scan_kernel(int* __restrict__ counts_cursor, int* __restrict__ row_ptr, int N) {
    __shared__ int s_wsum[16];
    __shared__ int s_carry;
    int t = threadIdx.x;
    int lane = t & 63, wid = t >> 6;
    if (t == 0) { s_carry = 0; row_ptr[0] = 0; }
    __syncthreads();
    for (int start = 0; start < N; start += 1024) {
        int i = start + t;
        int v = (i < N) ? counts_cursor[i] : 0;
        int s = v;
        #pragma unroll
        for (int d = 1; d < 64; d <<= 1) {
            int u = __shfl_up(s, d);
            if (lane >= d) s += u;
        }
        if (lane == 63) s_wsum[wid] = s;
        __syncthreads();
        if (wid == 0) {
            int w = (lane < 16) ? s_wsum[lane] : 0;
            #pragma unroll
            for (int d = 1; d < 16; d <<= 1) {
                int u = __shfl_up(w, d);
                if (lane >= d) w += u;
            }
            if (lane < 16) s_wsum[lane] = w;
        }
        __syncthreads();
        int incl = s + (wid ? s_wsum[wid - 1] : 0) + s_carry;
        if (i < N) { row_ptr[i + 1] = incl; counts_cursor[i] = incl - v; }
        __syncthreads();
        if (t == 0) s_carry += s_wsum[15];
        __syncthreads();
    }
}

__global__ void fill_kernel(const int* __restrict__ ei, int E, int N,
                            int* __restrict__ cursor, int* __restrict__ col) {
    int i = blockIdx.x * blockDim.x + threadIdx.x;
    int Et = E + N;
    if (i >= Et) return;
    int s, d;
    if (i < E) { s = ei[i]; d = ei[E + i]; } else { s = d = i - E; }
    int pos = atomicAdd(&cursor[d], 1);
    col[pos] = s;
}

// ---------------- fp32 -> bf16 convert (x, once, so GEMM1 A re-reads are 2B/elem) ----------------
__global__ void convert_bf16(const float* __restrict__ in, unsigned short* __restrict__ outb, int len4) {
    int i = blockIdx.x * blockDim.x + threadIdx.x;
    if (i >= len4) return;
    float4 v = ((const float4*)in)[i];
    ushortx4 o;
    o[0] = f2bf(v.x); o[1] = f2bf(v.y); o[2] = f2bf(v.z); o[3] = f2bf(v.w);
    *(ushortx4*)(outb + (size_t)i * 4) = o;
}

// ---------------- transpose: B[K][N] fp32 -> T[N][K] bf16 ----------------
__global__ __launch_bounds__(256) void transpose_bf16(const float* __restrict__ B,
        unsigned short* __restrict__ T, int K, int N) {
    __shared__ float tile[32][33];
    int n0 = blockIdx.x * 32, k0 = blockIdx.y * 32;
    int tx = threadIdx.x, ty = threadIdx.y;  // block (32, 8)
    #pragma unroll
    for (int i = 0; i < 32; i += 8)
        tile[ty + i][tx] = B[(size_t)(k0 + ty + i) * N + n0 + tx];
    __syncthreads();
    #pragma unroll
    for (int i = 0; i < 32; i += 8)
        T[(size_t)(n0 + ty + i) * K + k0 + tx] = f2bf(tile[tx][ty + i]);
}

// ---------------- bf16 MFMA GEMM: C = A @ Bt^T ----------------
// A: bf16 bits [M][K]. Bt: [N][K] bf16 bits. 128xTN tile, BK=32, 4 waves of 64x(TN/2).
#define LDK 40  // 32 + 8 pad (shorts) -> 80 B row stride, 2-way (free) frag-read conflicts
template <bool OUT_BF16, int TN>
__global__ __launch_bounds__(256) void gemm_1t(const unsigned short* __restrict__ A,
        const unsigned short* __restrict__ Bt, void* __restrict__ Cout, int M, int N, int K) {
    constexpr int JN = TN / 32;                  // B frags per wave (TN=128 -> 4, TN=64 -> 2)
    __shared__ unsigned short As[128 * LDK];
    __shared__ unsigned short Bs[TN * LDK];
    int t = threadIdx.x;
    int lane = t & 63, wave = t >> 6;
    int wm = (wave >> 1) * 64, wn = (wave & 1) * (TN / 2);
    int q = lane >> 4, l16 = lane & 15;
    int row0 = blockIdx.y * 128, col0 = blockIdx.x * TN;

    floatx4 acc[4][JN] = {};

    int sg = (t & 7) * 4;   // k-offset (4-elem granule)
    int sr = t >> 3;        // row 0..31 per pass

    for (int kt = 0; kt < K; kt += 32) {
        #pragma unroll
        for (int p = 0; p < 4; p++) {
            int r = sr + p * 32;
            int ga = min(row0 + r, M - 1);        // clamp ragged M (stores are guarded)
            *(ushortx4*)&As[r * LDK + sg] = *(const ushortx4*)(A + (size_t)ga * K + kt + sg);
        }
        #pragma unroll
        for (int p = 0; p < TN / 32; p++) {
            int r = sr + p * 32;
            *(ushortx4*)&Bs[r * LDK + sg] = *(const ushortx4*)(Bt + (size_t)(col0 + r) * K + kt + sg);
        }
        __syncthreads();
        bf16x8 af[4], bfr[JN];
        #pragma unroll
        for (int i = 0; i < 4; i++)
            af[i] = *(const bf16x8*)&As[(wm + i * 16 + l16) * LDK + q * 8];
        #pragma unroll
        for (int j = 0; j < JN; j++)
            bfr[j] = *(const bf16x8*)&Bs[(wn + j * 16 + l16) * LDK + q * 8];
        #pragma unroll
        for (int i = 0; i < 4; i++)
            #pragma unroll
            for (int j = 0; j < JN; j++)
                acc[i][j] = __builtin_amdgcn_mfma_f32_16x16x32_bf16(af[i], bfr[j], acc[i][j], 0, 0, 0);
        __syncthreads();
    }
    #pragma unroll
    for (int i = 0; i < 4; i++) {
        #pragma unroll
        for (int r = 0; r < 4; r++) {
            int grow = row0 + wm + i * 16 + q * 4 + r;
            if (grow < M) {
                if constexpr (OUT_BF16) {
                    unsigned short* cp = (unsigned short*)Cout + (size_t)grow * N + col0 + wn + l16;
                    #pragma unroll
                    for (int j = 0; j < JN; j++) cp[j * 16] = f2bf(acc[i][j][r]);
                } else {
                    float* cp = (float*)Cout + (size_t)grow * N + col0 + wn + l16;
                    #pragma unroll
                    for (int j = 0; j < JN; j++) cp[j * 16] = acc[i][j][r];
                }
            }
        }
    }
}

// ---------------- per-node attention logits, layer 1 (H=4, C=256), bf16 h1 ----------------
__global__ void s1_kernel(const unsigned short* __restrict__ h1b, const float* __restrict__ a_src,
                          const float* __restrict__ a_dst, float* __restrict__ ssrc,
                          float* __restrict__ sdst, int N) {
    int wid = (blockIdx.x * blockDim.x + threadIdx.x) >> 6;
    int lane = threadIdx.x & 63;
    if (wid >= N) return;
    const unsigned short* row = h1b + (size_t)wid * 1024;
    #pragma unroll
    for (int h = 0; h < 4; h++) {
        ushortx4 v = *(const ushortx4*)(row + h * 256 + lane * 4);
        float4 a = ((const float4*)a_src)[h * 64 + lane];
        float4 d = ((const float4*)a_dst)[h * 64 + lane];
        float v0 = bf2f(v[0]), v1 = bf2f(v[1]), v2 = bf2f(v[2]), v3 = bf2f(v[3]);
        float s = v0 * a.x + v1 * a.y + v2 * a.z + v3 * a.w;
        float t = v0 * d.x + v1 * d.y + v2 * d.z + v3 * d.w;
        for (int off = 32; off; off >>= 1) { s += __shfl_xor(s, off); t += __shfl_xor(t, off); }
        if (lane == 0) { ssrc[wid * 4 + h] = s; sdst[wid * 4 + h] = t; }
    }
}

// ---------------- per-node attention logits, layer 2 (H=1, C=256), bf16 h2 ----------------
__global__ void s2_kernel(const unsigned short* __restrict__ h2b, const float* __restrict__ a_src,
                          const float* __restrict__ a_dst, float* __restrict__ ssrc,
                          float* __restrict__ sdst, int N) {
    int wid = (blockIdx.x * blockDim.x + threadIdx.x) >> 6;
    int lane = threadIdx.x & 63;
    if (wid >= N) return;
    ushortx4 v = *(const ushortx4*)(h2b + (size_t)wid * 256 + lane * 4);
    float4 a = ((const float4*)a_src)[lane];
    float4 d = ((const float4*)a_dst)[lane];
    float v0 = bf2f(v[0]), v1 = bf2f(v[1]), v2 = bf2f(v[2]), v3 = bf2f(v[3]);
    float s = v0 * a.x + v1 * a.y + v2 * a.z + v3 * a.w;
    float t = v0 * d.x + v1 * d.y + v2 * d.z + v3 * d.w;
    for (int off = 32; off; off >>= 1) { s += __shfl_xor(s, off); t += __shfl_xor(t, off); }
    if (lane == 0) { ssrc[wid] = s; sdst[wid] = t; }
}

// ---------------- per-edge softmax weights, layer 1 (H=4) ----------------
__global__ __launch_bounds__(256) void alpha1_kernel(const float* __restrict__ ssrc,
        const float* __restrict__ sdst, const int* __restrict__ row_ptr,
        const int* __restrict__ col, float* __restrict__ wx, float* __restrict__ den, int N) {
    int wid = (blockIdx.x * blockDim.x + threadIdx.x) >> 6;
    int lane = threadIdx.x & 63;
    if (wid >= N) return;
    int base = row_ptr[wid];
    int deg = row_ptr[wid + 1] - base;
    float sd0 = sdst[wid * 4 + 0], sd1 = sdst[wid * 4 + 1];
    float sd2 = sdst[wid * 4 + 2], sd3 = sdst[wid * 4 + 3];
    float m0 = -1e30f, m1 = -1e30f, m2 = -1e30f, m3 = -1e30f;
    for (int i = lane; i < deg; i += 64) {
        int s = col[base + i];
        const float* sp = ssrc + s * 4;
        m0 = fmaxf(m0, lrelu(sp[0] + sd0));
        m1 = fmaxf(m1, lrelu(sp[1] + sd1));
        m2 = fmaxf(m2, lrelu(sp[2] + sd2));
        m3 = fmaxf(m3, lrelu(sp[3] + sd3));
    }
    #pragma unroll
    for (int off = 32; off; off >>= 1) {
        m0 = fmaxf(m0, __shfl_xor(m0, off));
        m1 = fmaxf(m1, __shfl_xor(m1, off));
        m2 = fmaxf(m2, __shfl_xor(m2, off));
        m3 = fmaxf(m3, __shfl_xor(m3, off));
    }
    float d0 = 0.f, d1 = 0.f, d2 = 0.f, d3 = 0.f;
    for (int i = lane; i < deg; i += 64) {
        int s = col[base + i];
        const float* sp = ssrc + s * 4;
        float4 w4;
        w4.x = __expf(lrelu(sp[0] + sd0) - m0); d0 += w4.x;
        w4.y = __expf(lrelu(sp[1] + sd1) - m1); d1 += w4.y;
        w4.z = __expf(lrelu(sp[2] + sd2) - m2); d2 += w4.z;
        w4.w = __expf(lrelu(sp[3] + sd3) - m3); d3 += w4.w;
        *(float4*)(wx + (size_t)(base + i) * 4) = w4;
    }
    #pragma unroll
    for (int off = 32; off; off >>= 1) {
        d0 += __shfl_xor(d0, off);
        d1 += __shfl_xor(d1, off);
        d2 += __shfl_xor(d2, off);
        d3 += __shfl_xor(d3, off);
    }
    if (lane == 0) {
        den[wid * 4 + 0] = d0; den[wid * 4 + 1] = d1;
        den[wid * 4 + 2] = d2; den[wid * 4 + 3] = d3;
    }
}

// ---------------- per-edge softmax weights, layer 2 (H=1) ----------------
__global__ __launch_bounds__(256) void alpha2_kernel(const float* __restrict__ ssrc,
        const float* __restrict__ sdst, const int* __restrict__ row_ptr,
        const int* __restrict__ col, float* __restrict__ wx, float* __restrict__ den, int N) {
    int wid = (blockIdx.x * blockDim.x + threadIdx.x) >> 6;
    int lane = threadIdx.x & 63;
    if (wid >= N) return;
    int base = row_ptr[wid];
    int deg = row_ptr[wid + 1] - base;
    float sd = sdst[wid];
    float m = -1e30f;
    for (int i = lane; i < deg; i += 64) {
        int s = col[base + i];
        m = fmaxf(m, lrelu(ssrc[s] + sd));
    }
    #pragma unroll
    for (int off = 32; off; off >>= 1) m = fmaxf(m, __shfl_xor(m, off));
    float d = 0.f;
    for (int i = lane; i < deg; i += 64) {
        int s = col[base + i];
        float x = __expf(lrelu(ssrc[s] + sd) - m);
        d += x;
        wx[base + i] = x;
    }
    #pragma unroll
    for (int off = 32; off; off >>= 1) d += __shfl_xor(d, off);
    if (lane == 0) den[wid] = d;
}

// ---------------- layer-1 aggregation: 2-edge unrolled gather, 16B/lane loads ----------------
// lane l: covers head hA=l>>5 (channels (l&31)*8..+8) and head hA+2 (same channels).
__global__ __launch_bounds__(256) void agg1_kernel(const unsigned short* __restrict__ h1b,
        const float* __restrict__ wx, const float* __restrict__ den,
        const int* __restrict__ row_ptr, const int* __restrict__ col,
        const float* __restrict__ bias, unsigned short* __restrict__ outb, int N) {
    int wid = (blockIdx.x * blockDim.x + threadIdx.x) >> 6;
    int lane = threadIdx.x & 63;
    if (wid >= N) return;
    int base = row_ptr[wid];
    int deg  = row_ptr[wid + 1] - base;
    int hA   = lane >> 5;              // head 0/1; second head = hA+2
    int cA   = (lane & 31) * 8;
    int offA = hA * 256 + cA;          // shorts; 16B aligned
    int offB = offA + 512;
    float accA[8] = {}, accB[8] = {};
    int i = 0;
    for (; i + 1 < deg; i += 2) {
        int s0 = col[base + i], s1 = col[base + i + 1];
        float4 w0 = *(const float4*)(wx + (size_t)(base + i) * 4);
        float4 w1 = *(const float4*)(wx + (size_t)(base + i + 1) * 4);
        const unsigned short* r0 = h1b + (size_t)s0 * 1024;
        const unsigned short* r1 = h1b + (size_t)s1 * 1024;
        ushortx8 vA0 = *(const ushortx8*)(r0 + offA);
        ushortx8 vB0 = *(const ushortx8*)(r0 + offB);
        ushortx8 vA1 = *(const ushortx8*)(r1 + offA);
        ushortx8 vB1 = *(const ushortx8*)(r1 + offB);
        float wA0 = hA ? w0.y : w0.x, wB0 = hA ? w0.w : w0.z;
        float wA1 = hA ? w1.y : w1.x, wB1 = hA ? w1.w : w1.z;
        #pragma unroll
        for (int j = 0; j < 8; j++) {
            accA[j] += wA0 * bf2f(vA0[j]) + wA1 * bf2f(vA1[j]);
            accB[j] += wB0 * bf2f(vB0[j]) + wB1 * bf2f(vB1[j]);
        }
    }
    if (i < deg) {
        int s0 = col[base + i];
        float4 w0 = *(const float4*)(wx + (size_t)(base + i) * 4);
        const unsigned short* r0 = h1b + (size_t)s0 * 1024;
        ushortx8 vA0 = *(const ushortx8*)(r0 + offA);
        ushortx8 vB0 = *(const ushortx8*)(r0 + offB);
        float wA0 = hA ? w0.y : w0.x, wB0 = hA ? w0.w : w0.z;
        #pragma unroll
        for (int j = 0; j < 8; j++) {
            accA[j] += wA0 * bf2f(vA0[j]);
            accB[j] += wB0 * bf2f(vB0[j]);
        }
    }
    float iA = 1.f / (den[wid * 4 + hA] + 1e-16f);
    float iB = 1.f / (den[wid * 4 + 2 + hA] + 1e-16f);
    const float* bA = bias + hA * 256 + cA;
    const float* bB = bA + 512;
    ushortx8 oA, oB;
    #pragma unroll
    for (int j = 0; j < 8; j++) {
        oA[j] = f2bf(eluf(accA[j] * iA + bA[j]));
        oB[j] = f2bf(eluf(accB[j] * iB + bB[j]));
    }
    *(ushortx8*)(outb + (size_t)wid * 1024 + offA) = oA;
    *(ushortx8*)(outb + (size_t)wid * 1024 + offB) = oB;
}

// ---------------- layer-2 aggregation: 2-edge unrolled gather; fp32 out ----------------
__global__ __launch_bounds__(256) void agg2_kernel(const unsigned short* __restrict__ h2b,
        const float* __restrict__ wx, const float* __restrict__ den,
        const int* __restrict__ row_ptr, const int* __restrict__ col,
        const float* __restrict__ bias, float* __restrict__ out, int N) {
    int wid = (blockIdx.x * blockDim.x + threadIdx.x) >> 6;
    int lane = threadIdx.x & 63;
    if (wid >= N) return;
    int base = row_ptr[wid];
    int deg = row_ptr[wid + 1] - base;
    float4 a = {0, 0, 0, 0};
    int c = lane * 4;
    int i = 0;
    for (; i + 1 < deg; i += 2) {
        int s0 = col[base + i], s1 = col[base + i + 1];
        float x0 = wx[base + i], x1 = wx[base + i + 1];
        ushortx4 v0 = *(const ushortx4*)(h2b + (size_t)s0 * 256 + c);
        ushortx4 v1 = *(const ushortx4*)(h2b + (size_t)s1 * 256 + c);
        a.x += x0 * bf2f(v0[0]) + x1 * bf2f(v1[0]);
        a.y += x0 * bf2f(v0[1]) + x1 * bf2f(v1[1]);
        a.z += x0 * bf2f(v0[2]) + x1 * bf2f(v1[2]);
        a.w += x0 * bf2f(v0[3]) + x1 * bf2f(v1[3]);
    }
    if (i < deg) {
        int s0 = col[base + i];
        float x0 = wx[base + i];
        ushortx4 v0 = *(const ushortx4*)(h2b + (size_t)s0 * 256 + c);
        a.x += x0 * bf2f(v0[0]); a.y += x0 * bf2f(v0[1]);
        a.z += x0 * bf2f(v0[2]); a.w += x0 * bf2f(v0[3]);
    }
    float inv = 1.f / (den[wid] + 1e-16f);
    float4 o;
    o.x = eluf(a.x * inv + bias[c + 0]);
    o.y = eluf(a.y * inv + bias[c + 1]);
    o.z = eluf(a.z * inv + bias[c + 2]);
    o.w = eluf(a.w * inv + bias[c + 3]);
    *(float4*)(out + (size_t)wid * 256 + c) = o;
}

// ---------------- mean over nodes -> graph_features [256] ----------------
__global__ void mean_kernel(const float* __restrict__ h, float* __restrict__ gf, int N) {
    int c = threadIdx.x;
    int per = (N + gridDim.x - 1) / gridDim.x;
    int n0 = blockIdx.x * per;
    int n1 = min(N, n0 + per);
    float acc = 0.f;
    for (int n = n0; n < n1; n++) acc += h[(size_t)n * 256 + c];
    atomicAdd(&gf[c], acc * (1.0f / N));
}

// ---------------- influence head: sigmoid(relu(h@Wp1+bp1)@Wp2+bp2), 4 nodes/block ----------------
__global__ __launch_bounds__(128) void infl_kernel(const float* __restrict__ h,
        const float* __restrict__ Wp1, const float* __restrict__ bp1,
        const float* __restrict__ Wp2, const float* __restrict__ bp2,
        float* __restrict__ infl, int N) {
    __shared__ float sh[4][256];
    __shared__ float red[4][128];
    int nb = blockIdx.x * 4;
    int t = threadIdx.x;
    #pragma unroll
    for (int r = 0; r < 4; r++) {
        int n = nb + r;
        if (n < N) {
            sh[r][t] = h[(size_t)n * 256 + t];
            sh[r][t + 128] = h[(size_t)n * 256 + t + 128];
        }
    }
    __syncthreads();
    float acc0 = bp1[t], acc1 = acc0, acc2 = acc0, acc3 = acc0;
    for (int k = 0; k < 256; k++) {
        float w = Wp1[k * 128 + t];
        acc0 += sh[0][k] * w;
        acc1 += sh[1][k] * w;
        acc2 += sh[2][k] * w;
        acc3 += sh[3][k] * w;
    }
    float w2 = Wp2[t];
    red[0][t] = fmaxf(acc0, 0.f) * w2;
    red[1][t] = fmaxf(acc1, 0.f) * w2;
    red[2][t] = fmaxf(acc2, 0.f) * w2;
    red[3][t] = fmaxf(acc3, 0.f) * w2;
    __syncthreads();
    for (int s = 64; s > 0; s >>= 1) {
        if (t < s) {
            red[0][t] += red[0][t + s];
            red[1][t] += red[1][t + s];
            red[2][t] += red[2][t + s];
            red[3][t] += red[3][t + s];
        }
        __syncthreads();
    }
    if (t < 4) {
        int n = nb + t;
        if (n < N) {
            float v = red[t][0] + bp2[0];
            infl[n] = 1.f / (1.f + __expf(-v));
        }
    }
}

extern "C" void kernel_launch(void* const* d_in, const int* in_sizes, int n_in,
                              void* d_out, int out_size, void* d_ws, size_t ws_size,
                              hipStream_t stream) {
    const float* x   = (const float*)d_in[0];
    const int*   ei  = (const int*)d_in[1];
    const float* W1  = (const float*)d_in[2];
    const float* as1 = (const float*)d_in[3];
    const float* ad1 = (const float*)d_in[4];
    const float* b1  = (const float*)d_in[5];
    const float* W2  = (const float*)d_in[6];
    const float* as2 = (const float*)d_in[7];
    const float* ad2 = (const float*)d_in[8];
    const float* b2  = (const float*)d_in[9];
    const float* Wp1 = (const float*)d_in[10];
    const float* bp1 = (const float*)d_in[11];
    const float* Wp2 = (const float*)d_in[12];
    const float* bp2 = (const float*)d_in[13];

    const int N  = in_sizes[0] / 384;   // 20000
    const int E  = in_sizes[1] / 2;     // 320000
    const int Et = E + N;

    // ---- workspace layout ----
    char* wsp = (char*)d_ws;
    unsigned short* h1b  = (unsigned short*)wsp; wsp += (size_t)N * 1024 * sizeof(short); // GEMM1 out, bf16
    unsigned short* h1eb = (unsigned short*)wsp; wsp += (size_t)N * 1024 * sizeof(short); // agg1 out, bf16
    unsigned short* h2b  = (unsigned short*)wsp; wsp += (size_t)N * 256  * sizeof(short); // GEMM2 out, bf16
    unsigned short* xb   = (unsigned short*)wsp; wsp += (size_t)N * 384  * sizeof(short); // x, bf16
    unsigned short* w1t  = (unsigned short*)wsp; wsp += (size_t)1024 * 384 * sizeof(short);
    unsigned short* w2t  = (unsigned short*)wsp; wsp += (size_t)256 * 1024 * sizeof(short);
    float* ss1 = (float*)wsp; wsp += (size_t)N * 4 * sizeof(float);
    float* sd1 = (float*)wsp; wsp += (size_t)N * 4 * sizeof(float);
    float* ss2 = (float*)wsp; wsp += (size_t)N * sizeof(float);
    float* sd2 = (float*)wsp; wsp += (size_t)N * sizeof(float);
    float* den1 = (float*)wsp; wsp += (size_t)N * 4 * sizeof(float);
    float* den2 = (float*)wsp; wsp += (size_t)N * sizeof(float);
    float* wx1  = (float*)wsp; wsp += (size_t)Et * 4 * sizeof(float);
    float* wx2  = (float*)wsp; wsp += (size_t)Et * sizeof(float);
    int* row_ptr = (int*)wsp; wsp += (size_t)(N + 1) * sizeof(int);
    int* cursor  = (int*)wsp; wsp += (size_t)N * sizeof(int);
    int* col     = (int*)wsp;

    float* out_h  = (float*)d_out;             // [N,256]
    float* out_gf = out_h + (size_t)N * 256;   // [256]
    float* out_if = out_gf + 256;              // [N]

    // CSR build
    hipMemsetAsync(cursor, 0, (size_t)N * sizeof(int), stream);
    count_kernel<<<(Et + 255) / 256, 256, 0, stream>>>(ei, E, N, cursor);
    scan_kernel<<<1, 1024, 0, stream>>>(cursor, row_ptr, N);
    fill_kernel<<<(Et + 255) / 256, 256, 0, stream>>>(ei, E, N, cursor, col);

    // input/weight prep
    convert_bf16<<<(N * 384 / 4 + 255) / 256, 256, 0, stream>>>(x, xb, N * 384 / 4);
    transpose_bf16<<<dim3(1024 / 32, 384 / 32), dim3(32, 8), 0, stream>>>(W1, w1t, 384, 1024);
    transpose_bf16<<<dim3(256 / 32, 1024 / 32), dim3(32, 8), 0, stream>>>(W2, w2t, 1024, 256);

    // layer 1
    gemm_1t<true, 128><<<dim3(1024 / 128, (N + 127) / 128), 256, 0, stream>>>(
        xb, w1t, h1b, N, 1024, 384);
    s1_kernel<<<(N + 3) / 4, 256, 0, stream>>>(h1b, as1, ad1, ss1, sd1, N);
    alpha1_kernel<<<(N + 3) / 4, 256, 0, stream>>>(ss1, sd1, row_ptr, col, wx1, den1, N);
    agg1_kernel<<<(N + 3) / 4, 256, 0, stream>>>(h1b, wx1, den1, row_ptr, col, b1, h1eb, N);

    // layer 2
    gemm_1t<true, 64><<<dim3(256 / 64, (N + 127) / 128), 256, 0, stream>>>(
        h1eb, w2t, h2b, N, 256, 1024);
    s2_kernel<<<(N + 3) / 4, 256, 0, stream>>>(h2b, as2, ad2, ss2, sd2, N);
    alpha2_kernel<<<(N + 3) / 4, 256, 0, stream>>>(ss2, sd2, row_ptr, col, wx2, den2, N);
    agg2_kernel<<<(N + 3) / 4, 256, 0, stream>>>(h2b, wx2, den2, row_ptr, col, b2, out_h, N);

    // outputs 2 & 3
    hipMemsetAsync(out_gf, 0, 256 * sizeof(float), stream);
    mean_kernel<<<80, 256, 0, stream>>>(out_h, out_gf, N);
    infl_kernel<<<(N + 3) / 4, 128, 0, stream>>>(out_h, Wp1, bp1, Wp2, bp2, out_if, N);
}